// Round 1
// baseline (657.917 us; speedup 1.0000x reference)
//
#include <hip/hip_runtime.h>

// GIN (5 layers) + BN + pool + MLP head, fused pipeline for MI355X. Round 3.
// R2 was grid-occupancy-bound: 782 blocks (64 nodes/block) = 3 blocks/CU ->
// OccupancyPercent 23%, VALUBusy 15%, HBM 17%, latency-exposed gather.
// R3: 32 nodes per 256-thread block -> grid 1563 (~6.1 blocks/CU, 24 waves/CU).
//  - layer_kernel: gather kk-loop 2 iters (wave = 8 nodes), GEMM 2x4 per thread
//  - xw_kernel: same 32-row tiling
//  - LDS 17.9KB -> 8.7KB/block

constexpr int N = 50000;
constexpr int E = 800000;
constexpr int G = 128;
constexpr int MAXDEG = 64;
constexpr float BN_EPS = 1e-5f;

__device__ inline float4 ld4(const float* p) { return *(const float4*)p; }
__device__ inline void st4(float* p, float4 v) { *(float4*)p = v; }
__device__ inline float4 add4(float4 a, float4 b) {
    return make_float4(a.x + b.x, a.y + b.y, a.z + b.z, a.w + b.w);
}

__global__ __launch_bounds__(256) void count_fill_kernel(
    const int* __restrict__ ei, int* __restrict__ deg, int* __restrict__ ell)
{
    int e = blockIdx.x * 256 + threadIdx.x;
    if (e < E) {
        int s = ei[e];
        int d = ei[E + e];
        int slot = atomicAdd(&deg[d], 1);
        if (slot < MAXDEG) ell[d * MAXDEG + slot] = s;
    }
}

// pad each ELL row to a multiple of 4 slots with the zero-row index N
__global__ __launch_bounds__(256) void pad_kernel(
    const int* __restrict__ deg, int* __restrict__ ell)
{
    int n = blockIdx.x * 256 + threadIdx.x;
    if (n < N) {
        int dgc = min(deg[n], MAXDEG);
        int p = (dgc + 3) & ~3;
        for (int s = dgc; s < p; s++) ell[n * MAXDEG + s] = N;
    }
}

// out[n][64] = x[n][128] @ W[128][64]; 32 rows per block, no LDS
__global__ __launch_bounds__(256) void xw_kernel(
    const float* __restrict__ x, const float* __restrict__ W, float* __restrict__ out)
{
    int tid = threadIdx.x;
    int ty = tid >> 4, tx = tid & 15;    // ty 0..15 -> 2 rows each
    int base = blockIdx.x * 32;

    float acc[2][4];
#pragma unroll
    for (int r = 0; r < 2; r++)
#pragma unroll
        for (int cc = 0; cc < 4; cc++) acc[r][cc] = 0.f;

    int rr[2];
#pragma unroll
    for (int r = 0; r < 2; r++) rr[r] = min(base + 2 * ty + r, N - 1);

#pragma unroll 4
    for (int c = 0; c < 128; c++) {
        float4 w4 = ld4(W + c * 64 + 4 * tx);
#pragma unroll
        for (int r = 0; r < 2; r++) {
            float a = x[(size_t)rr[r] * 128 + c];
            acc[r][0] += a * w4.x; acc[r][1] += a * w4.y;
            acc[r][2] += a * w4.z; acc[r][3] += a * w4.w;
        }
    }
#pragma unroll
    for (int r = 0; r < 2; r++) {
        int node = base + 2 * ty + r;
        if (node < N)
            st4(out + (size_t)node * 64 + 4 * tx,
                make_float4(acc[r][0], acc[r][1], acc[r][2], acc[r][3]));
    }
}

// Fused GIN layer. hin has N+1 rows (row N = zeros). 32 nodes per block.
// FIRST:  v = relu(own + sum_src + b1a)           then GEMM2(W2,b2)+relu
// !FIRST: v = scale*(own+sum) + (1+deg)*shift, GEMM1(W1,b1)+relu (in-place), GEMM2+relu
// Writes hout (pre-BN, post-relu) and accumulates channel sum/sumsq into statsOut.
template <bool FIRST>
__global__ __launch_bounds__(256) void layer_kernel(
    const float* __restrict__ hin, const int* __restrict__ ell, const int* __restrict__ deg,
    const float* __restrict__ statsPrev, const float* __restrict__ gamma, const float* __restrict__ beta,
    const float* __restrict__ bias0,
    const float* __restrict__ W1, const float* __restrict__ b1,
    const float* __restrict__ W2, const float* __restrict__ b2,
    float* __restrict__ hout, float* __restrict__ statsOut)
{
    __shared__ float sV[32 * 68];   // stride 68
    __shared__ float sStat[128];

    int tid = threadIdx.x, lane = tid & 63, wv = tid >> 6;
    if (tid < 128) sStat[tid] = 0.f;

    int base = blockIdx.x * 32;
    int n4 = lane >> 4, f = lane & 15;   // node-sub, feature-quad

    // per-lane channel quad f*4..f*4+3 epilogue params
    float4 sc4 = make_float4(1.f, 1.f, 1.f, 1.f);
    float4 sh4 = make_float4(0.f, 0.f, 0.f, 0.f);
    float4 b04 = make_float4(0.f, 0.f, 0.f, 0.f);
    if constexpr (FIRST) {
        b04 = ld4(bias0 + 4 * f);
    } else {
        float4 s1 = ld4(statsPrev + 4 * f);
        float4 s2 = ld4(statsPrev + 64 + 4 * f);
        float4 g4 = ld4(gamma + 4 * f);
        float4 be4 = ld4(beta + 4 * f);
        float mx = s1.x / N, my = s1.y / N, mz = s1.z / N, mw = s1.w / N;
        sc4.x = g4.x * rsqrtf(s2.x / N - mx * mx + BN_EPS);
        sc4.y = g4.y * rsqrtf(s2.y / N - my * my + BN_EPS);
        sc4.z = g4.z * rsqrtf(s2.z / N - mz * mz + BN_EPS);
        sc4.w = g4.w * rsqrtf(s2.w / N - mw * mw + BN_EPS);
        sh4.x = be4.x - mx * sc4.x; sh4.y = be4.y - my * sc4.y;
        sh4.z = be4.z - mz * sc4.z; sh4.w = be4.w - mw * sc4.w;
    }

    // ---- phase A: gather; each wave handles 4 nodes at a time, 2 rounds ----
#pragma unroll
    for (int kk = 0; kk < 2; kk++) {
        int node = base + wv * 8 + kk * 4 + n4;
        int nd = (node < N) ? node : N;
        int dg = (node < N) ? deg[node] : 0;
        int dgc = min(dg, MAXDEG);
        int p = (dgc + 3) & ~3;
        const int* row = ell + (size_t)nd * MAXDEG;

        float4 a0 = make_float4(0.f, 0.f, 0.f, 0.f), a1 = a0, a2 = a0, a3 = a0;
        for (int j = 0; j < p; j += 4) {
            int4 iv = *(const int4*)(row + j);
            a0 = add4(a0, ld4(hin + (size_t)iv.x * 64 + 4 * f));
            a1 = add4(a1, ld4(hin + (size_t)iv.y * 64 + 4 * f));
            a2 = add4(a2, ld4(hin + (size_t)iv.z * 64 + 4 * f));
            a3 = add4(a3, ld4(hin + (size_t)iv.w * 64 + 4 * f));
        }
        float4 own = ld4(hin + (size_t)nd * 64 + 4 * f);
        float4 s = add4(add4(add4(a0, a1), add4(a2, a3)), own);
        float4 v;
        if constexpr (FIRST) {
            v = make_float4(fmaxf(s.x + b04.x, 0.f), fmaxf(s.y + b04.y, 0.f),
                            fmaxf(s.z + b04.z, 0.f), fmaxf(s.w + b04.w, 0.f));
        } else {
            float dsh = (float)(1 + dg);
            v = make_float4(sc4.x * s.x + dsh * sh4.x, sc4.y * s.y + dsh * sh4.y,
                            sc4.z * s.z + dsh * sh4.z, sc4.w * s.w + dsh * sh4.w);
        }
        st4(sV + (wv * 8 + kk * 4 + n4) * 68 + 4 * f, v);
    }
    __syncthreads();

    int ty = tid >> 4, tx = tid & 15;   // ty 0..15 -> rows 2*ty..2*ty+1

    if constexpr (!FIRST) {
        // ---- phase B: H = relu(V @ W1 + b1), in-place into sV ----
        float acc[2][4];
#pragma unroll
        for (int cc = 0; cc < 4; cc++) {
            float b = b1[4 * tx + cc];
            acc[0][cc] = b; acc[1][cc] = b;
        }
#pragma unroll 4
        for (int c = 0; c < 64; c++) {
            float4 w4 = ld4(W1 + c * 64 + 4 * tx);
#pragma unroll
            for (int r = 0; r < 2; r++) {
                float a = sV[(2 * ty + r) * 68 + c];
                acc[r][0] += a * w4.x; acc[r][1] += a * w4.y;
                acc[r][2] += a * w4.z; acc[r][3] += a * w4.w;
            }
        }
        __syncthreads();
#pragma unroll
        for (int r = 0; r < 2; r++)
            st4(sV + (2 * ty + r) * 68 + 4 * tx,
                make_float4(fmaxf(acc[r][0], 0.f), fmaxf(acc[r][1], 0.f),
                            fmaxf(acc[r][2], 0.f), fmaxf(acc[r][3], 0.f)));
        __syncthreads();
    }

    // ---- phase C: O = relu(V @ W2 + b2), store, stats ----
    float acc[2][4];
#pragma unroll
    for (int cc = 0; cc < 4; cc++) {
        float b = b2[4 * tx + cc];
        acc[0][cc] = b; acc[1][cc] = b;
    }
#pragma unroll 4
    for (int c = 0; c < 64; c++) {
        float4 w4 = ld4(W2 + c * 64 + 4 * tx);
#pragma unroll
        for (int r = 0; r < 2; r++) {
            float a = sV[(2 * ty + r) * 68 + c];
            acc[r][0] += a * w4.x; acc[r][1] += a * w4.y;
            acc[r][2] += a * w4.z; acc[r][3] += a * w4.w;
        }
    }
#pragma unroll
    for (int r = 0; r < 2; r++) {
        int node = base + 2 * ty + r;
        if (node < N) {
            float4 st;
            st.x = fmaxf(acc[r][0], 0.f); st.y = fmaxf(acc[r][1], 0.f);
            st.z = fmaxf(acc[r][2], 0.f); st.w = fmaxf(acc[r][3], 0.f);
            acc[r][0] = st.x; acc[r][1] = st.y; acc[r][2] = st.z; acc[r][3] = st.w;
            st4(hout + (size_t)node * 64 + 4 * tx, st);
        } else {
            acc[r][0] = acc[r][1] = acc[r][2] = acc[r][3] = 0.f;
        }
    }
#pragma unroll
    for (int cc = 0; cc < 4; cc++) {
        float s = 0.f, q = 0.f;
#pragma unroll
        for (int r = 0; r < 2; r++) { s += acc[r][cc]; q += acc[r][cc] * acc[r][cc]; }
        atomicAdd(&sStat[4 * tx + cc], s);
        atomicAdd(&sStat[64 + 4 * tx + cc], q);
    }
    __syncthreads();
    if (tid < 128) atomicAdd(&statsOut[tid], sStat[tid]);
}

// pooled[g] = scale*sum_{n in g} h[n] + cnt*shift; z=relu(p@fc1+b1); z@fc2+b2; log_softmax
__global__ __launch_bounds__(256) void pool_head_kernel(
    const float* __restrict__ h, const int* __restrict__ batch,
    const float* __restrict__ stats, const float* __restrict__ gamma, const float* __restrict__ beta,
    const float* __restrict__ fc1w, const float* __restrict__ fc1b,
    const float* __restrict__ fc2w, const float* __restrict__ fc2b,
    float* __restrict__ out)
{
    __shared__ float sacc[4][64];
    __shared__ float sp[64];
    __shared__ float sz[64];
    __shared__ float so[10];

    int g = blockIdx.x;
    int lane = threadIdx.x & 63, wv = threadIdx.x >> 6;

    int start, end;
    {
        int lo = 0, hi = N;
        while (lo < hi) { int mid = (lo + hi) >> 1; if (batch[mid] < g) lo = mid + 1; else hi = mid; }
        start = lo;
        lo = start; hi = N;
        while (lo < hi) { int mid = (lo + hi) >> 1; if (batch[mid] < g + 1) lo = mid + 1; else hi = mid; }
        end = lo;
    }

    float acc = 0.f;
    for (int node = start + wv; node < end; node += 4)
        acc += h[(size_t)node * 64 + lane];
    sacc[wv][lane] = acc;
    __syncthreads();

    if (wv == 0) {
        float mean = stats[lane] * (1.f / N);
        float var  = stats[64 + lane] * (1.f / N) - mean * mean;
        float sc = gamma[lane] * rsqrtf(var + BN_EPS);
        float sh = beta[lane] - mean * sc;
        float t = sacc[0][lane] + sacc[1][lane] + sacc[2][lane] + sacc[3][lane];
        sp[lane] = sc * t + (float)(end - start) * sh;
    }
    __syncthreads();
    if (wv == 0) {
        float a = fc1b[lane];
#pragma unroll
        for (int c = 0; c < 64; c++) a += sp[c] * fc1w[c * 64 + lane];
        sz[lane] = fmaxf(a, 0.f);
    }
    __syncthreads();
    if (wv == 0 && lane < 10) {
        float z = fc2b[lane];
#pragma unroll
        for (int j = 0; j < 64; j++) z += sz[j] * fc2w[j * 10 + lane];
        so[lane] = z;
    }
    __syncthreads();
    if (wv == 0 && lane < 10) {
        float m = -1e30f;
#pragma unroll
        for (int c = 0; c < 10; c++) m = fmaxf(m, so[c]);
        float s = 0.f;
#pragma unroll
        for (int c = 0; c < 10; c++) s += expf(so[c] - m);
        out[g * 10 + lane] = so[lane] - m - logf(s);
    }
}

extern "C" void kernel_launch(void* const* d_in, const int* in_sizes, int n_in,
                              void* d_out, int out_size, void* d_ws, size_t ws_size,
                              hipStream_t stream)
{
    const float* x    = (const float*)d_in[0];
    const int*   ei   = (const int*)  d_in[1];
    const int*   batch= (const int*)  d_in[2];
    const float* W1a  = (const float*)d_in[3];
    const float* b1a  = (const float*)d_in[4];
    const float* W1b  = (const float*)d_in[5];
    const float* b1b  = (const float*)d_in[6];
    const float* Wa   = (const float*)d_in[7];
    const float* ba   = (const float*)d_in[8];
    const float* Wb   = (const float*)d_in[9];
    const float* bb   = (const float*)d_in[10];
    const float* gammas = (const float*)d_in[11];
    const float* betas  = (const float*)d_in[12];
    const float* fc1w = (const float*)d_in[13];
    const float* fc1b = (const float*)d_in[14];
    const float* fc2w = (const float*)d_in[15];
    const float* fc2b = (const float*)d_in[16];
    float* out = (float*)d_out;

    // workspace carve
    char* w = (char*)d_ws;
    int*   deg   = (int*)w;                          // N ints        @ 0        (zeroed)
    float* stats = (float*)(w + 200000);             // 5*128 floats  @ 200000   (zeroed)
    int*   ell   = (int*)(w + 202752);               // N*64 ints
    float* bufA  = (float*)(w + 13002752);           // (N+1)*64 floats
    float* bufB  = (float*)(w + 25803008);           // (N+1)*64 floats

    hipMemsetAsync(d_ws, 0, 202560, stream);
    hipMemsetAsync(bufA + (size_t)N * 64, 0, 256, stream);   // zero row N
    hipMemsetAsync(bufB + (size_t)N * 64, 0, 256, stream);

    count_fill_kernel<<<(E + 255) / 256, 256, 0, stream>>>(ei, deg, ell);
    pad_kernel<<<(N + 255) / 256, 256, 0, stream>>>(deg, ell);
    xw_kernel<<<(N + 31) / 32, 256, 0, stream>>>(x, W1a, bufA);

    int nb = (N + 31) / 32;

    layer_kernel<true><<<nb, 256, 0, stream>>>(
        bufA, ell, deg, nullptr, nullptr, nullptr, b1a,
        nullptr, nullptr, W1b, b1b, bufB, stats);

    layer_kernel<false><<<nb, 256, 0, stream>>>(
        bufB, ell, deg, stats, gammas, betas, nullptr,
        Wa, ba, Wb, bb, bufA, stats + 128);

    layer_kernel<false><<<nb, 256, 0, stream>>>(
        bufA, ell, deg, stats + 128, gammas + 64, betas + 64, nullptr,
        Wa + 4096, ba + 64, Wb + 4096, bb + 64, bufB, stats + 256);

    layer_kernel<false><<<nb, 256, 0, stream>>>(
        bufB, ell, deg, stats + 256, gammas + 128, betas + 128, nullptr,
        Wa + 8192, ba + 128, Wb + 8192, bb + 128, bufA, stats + 384);

    layer_kernel<false><<<nb, 256, 0, stream>>>(
        bufA, ell, deg, stats + 384, gammas + 192, betas + 192, nullptr,
        Wa + 12288, ba + 192, Wb + 12288, bb + 192, bufB, stats + 512);

    pool_head_kernel<<<G, 256, 0, stream>>>(
        bufB, batch, stats + 512, gammas + 256, betas + 256,
        fc1w, fc1b, fc2w, fc2b, out);
}

// Round 2
// 548.322 us; speedup vs baseline: 1.1999x; 1.1999x over previous
//
#include <hip/hip_runtime.h>

// GIN (5 layers) + BN + pool + MLP head, fused pipeline for MI355X. Round 4.
// R2 (64 nodes/blk): 70us/layer, VALUBusy 15%, occ 23%. R3 (32 nodes/blk):
// occ 42% but 92us/layer -> gather is NOT wave-starved; it is ILP-starved:
// the j-loop (int4 idx -> 4 dependent float4) with runtime divergent bound
// can't pipeline, ~5 loads in flight/lane, full L2/L3 latency every 4 nbrs.
// R4: revert to 64-node blocks; pad ELL rows to multiples of 16; gather in
// 16-neighbor chunks (4 int4 + 16 float4 issued together -> ~20 loads in
// flight, one branch per 16 nbrs; padded slots hit the hot zero row in L1).

constexpr int N = 50000;
constexpr int E = 800000;
constexpr int G = 128;
constexpr int MAXDEG = 64;
constexpr float BN_EPS = 1e-5f;

__device__ inline float4 ld4(const float* p) { return *(const float4*)p; }
__device__ inline void st4(float* p, float4 v) { *(float4*)p = v; }
__device__ inline float4 add4(float4 a, float4 b) {
    return make_float4(a.x + b.x, a.y + b.y, a.z + b.z, a.w + b.w);
}

__global__ __launch_bounds__(256) void count_fill_kernel(
    const int* __restrict__ ei, int* __restrict__ deg, int* __restrict__ ell)
{
    int e = blockIdx.x * 256 + threadIdx.x;
    if (e < E) {
        int s = ei[e];
        int d = ei[E + e];
        int slot = atomicAdd(&deg[d], 1);
        if (slot < MAXDEG) ell[d * MAXDEG + slot] = s;
    }
}

// pad each ELL row to a multiple of 16 slots with the zero-row index N
__global__ __launch_bounds__(256) void pad_kernel(
    const int* __restrict__ deg, int* __restrict__ ell)
{
    int n = blockIdx.x * 256 + threadIdx.x;
    if (n < N) {
        int dgc = min(deg[n], MAXDEG);
        int p = (dgc + 15) & ~15;
        for (int s = dgc; s < p; s++) ell[n * MAXDEG + s] = N;
    }
}

// out[n][64] = x[n][128] @ W[128][64]; 64 rows per block, no LDS
__global__ __launch_bounds__(256) void xw_kernel(
    const float* __restrict__ x, const float* __restrict__ W, float* __restrict__ out)
{
    int tid = threadIdx.x;
    int ty = tid >> 4, tx = tid & 15;
    int base = blockIdx.x * 64;

    float acc[4][4];
#pragma unroll
    for (int r = 0; r < 4; r++)
#pragma unroll
        for (int cc = 0; cc < 4; cc++) acc[r][cc] = 0.f;

    int rr[4];
#pragma unroll
    for (int r = 0; r < 4; r++) rr[r] = min(base + 4 * ty + r, N - 1);

#pragma unroll 4
    for (int c = 0; c < 128; c++) {
        float4 w4 = ld4(W + c * 64 + 4 * tx);
#pragma unroll
        for (int r = 0; r < 4; r++) {
            float a = x[(size_t)rr[r] * 128 + c];
            acc[r][0] += a * w4.x; acc[r][1] += a * w4.y;
            acc[r][2] += a * w4.z; acc[r][3] += a * w4.w;
        }
    }
#pragma unroll
    for (int r = 0; r < 4; r++) {
        int node = base + 4 * ty + r;
        if (node < N)
            st4(out + (size_t)node * 64 + 4 * tx,
                make_float4(acc[r][0], acc[r][1], acc[r][2], acc[r][3]));
    }
}

// Fused GIN layer. hin has N+1 rows (row N = zeros). 64 nodes per block.
// FIRST:  v = relu(own + sum_src + b1a)           then GEMM2(W2,b2)+relu
// !FIRST: v = scale*(own+sum) + (1+deg)*shift, GEMM1(W1,b1)+relu (in-place), GEMM2+relu
// Writes hout (pre-BN, post-relu) and accumulates channel sum/sumsq into statsOut.
template <bool FIRST>
__global__ __launch_bounds__(256) void layer_kernel(
    const float* __restrict__ hin, const int* __restrict__ ell, const int* __restrict__ deg,
    const float* __restrict__ statsPrev, const float* __restrict__ gamma, const float* __restrict__ beta,
    const float* __restrict__ bias0,
    const float* __restrict__ W1, const float* __restrict__ b1,
    const float* __restrict__ W2, const float* __restrict__ b2,
    float* __restrict__ hout, float* __restrict__ statsOut)
{
    __shared__ float sV[64 * 68];   // stride 68
    __shared__ float sStat[128];

    int tid = threadIdx.x, lane = tid & 63, wv = tid >> 6;
    if (tid < 128) sStat[tid] = 0.f;

    int base = blockIdx.x * 64;
    int n4 = lane >> 4, f = lane & 15;   // node-sub, feature-quad

    // per-lane channel quad f*4..f*4+3 epilogue params
    float4 sc4 = make_float4(1.f, 1.f, 1.f, 1.f);
    float4 sh4 = make_float4(0.f, 0.f, 0.f, 0.f);
    float4 b04 = make_float4(0.f, 0.f, 0.f, 0.f);
    if constexpr (FIRST) {
        b04 = ld4(bias0 + 4 * f);
    } else {
        float4 s1 = ld4(statsPrev + 4 * f);
        float4 s2 = ld4(statsPrev + 64 + 4 * f);
        float4 g4 = ld4(gamma + 4 * f);
        float4 be4 = ld4(beta + 4 * f);
        float mx = s1.x / N, my = s1.y / N, mz = s1.z / N, mw = s1.w / N;
        sc4.x = g4.x * rsqrtf(s2.x / N - mx * mx + BN_EPS);
        sc4.y = g4.y * rsqrtf(s2.y / N - my * my + BN_EPS);
        sc4.z = g4.z * rsqrtf(s2.z / N - mz * mz + BN_EPS);
        sc4.w = g4.w * rsqrtf(s2.w / N - mw * mw + BN_EPS);
        sh4.x = be4.x - mx * sc4.x; sh4.y = be4.y - my * sc4.y;
        sh4.z = be4.z - mz * sc4.z; sh4.w = be4.w - mw * sc4.w;
    }

    // ---- phase A: gather; wave handles 4 nodes at a time, 16-neighbor chunks ----
#pragma unroll
    for (int kk = 0; kk < 4; kk++) {
        int node = base + wv * 16 + kk * 4 + n4;
        int nd = (node < N) ? node : N;
        int dg = (node < N) ? deg[node] : 0;
        int dgc = min(dg, MAXDEG);
        int p = (dgc + 15) & ~15;
        const int* row = ell + (size_t)nd * MAXDEG;

        float4 own = ld4(hin + (size_t)nd * 64 + 4 * f);
        float4 a0 = make_float4(0.f, 0.f, 0.f, 0.f), a1 = a0, a2 = a0, a3 = a0;
        for (int j = 0; j < p; j += 16) {
            int4 iv0 = *(const int4*)(row + j);
            int4 iv1 = *(const int4*)(row + j + 4);
            int4 iv2 = *(const int4*)(row + j + 8);
            int4 iv3 = *(const int4*)(row + j + 12);
            a0 = add4(a0, ld4(hin + (size_t)iv0.x * 64 + 4 * f));
            a1 = add4(a1, ld4(hin + (size_t)iv0.y * 64 + 4 * f));
            a2 = add4(a2, ld4(hin + (size_t)iv0.z * 64 + 4 * f));
            a3 = add4(a3, ld4(hin + (size_t)iv0.w * 64 + 4 * f));
            a0 = add4(a0, ld4(hin + (size_t)iv1.x * 64 + 4 * f));
            a1 = add4(a1, ld4(hin + (size_t)iv1.y * 64 + 4 * f));
            a2 = add4(a2, ld4(hin + (size_t)iv1.z * 64 + 4 * f));
            a3 = add4(a3, ld4(hin + (size_t)iv1.w * 64 + 4 * f));
            a0 = add4(a0, ld4(hin + (size_t)iv2.x * 64 + 4 * f));
            a1 = add4(a1, ld4(hin + (size_t)iv2.y * 64 + 4 * f));
            a2 = add4(a2, ld4(hin + (size_t)iv2.z * 64 + 4 * f));
            a3 = add4(a3, ld4(hin + (size_t)iv2.w * 64 + 4 * f));
            a0 = add4(a0, ld4(hin + (size_t)iv3.x * 64 + 4 * f));
            a1 = add4(a1, ld4(hin + (size_t)iv3.y * 64 + 4 * f));
            a2 = add4(a2, ld4(hin + (size_t)iv3.z * 64 + 4 * f));
            a3 = add4(a3, ld4(hin + (size_t)iv3.w * 64 + 4 * f));
        }
        float4 s = add4(add4(add4(a0, a1), add4(a2, a3)), own);
        float4 v;
        if constexpr (FIRST) {
            v = make_float4(fmaxf(s.x + b04.x, 0.f), fmaxf(s.y + b04.y, 0.f),
                            fmaxf(s.z + b04.z, 0.f), fmaxf(s.w + b04.w, 0.f));
        } else {
            float dsh = (float)(1 + dg);
            v = make_float4(sc4.x * s.x + dsh * sh4.x, sc4.y * s.y + dsh * sh4.y,
                            sc4.z * s.z + dsh * sh4.z, sc4.w * s.w + dsh * sh4.w);
        }
        st4(sV + (wv * 16 + kk * 4 + n4) * 68 + 4 * f, v);
    }
    __syncthreads();

    int ty = tid >> 4, tx = tid & 15;

    if constexpr (!FIRST) {
        // ---- phase B: H = relu(V @ W1 + b1), in-place into sV ----
        float acc[4][4];
#pragma unroll
        for (int cc = 0; cc < 4; cc++) {
            float b = b1[4 * tx + cc];
            acc[0][cc] = b; acc[1][cc] = b; acc[2][cc] = b; acc[3][cc] = b;
        }
#pragma unroll 4
        for (int c = 0; c < 64; c++) {
            float4 w4 = ld4(W1 + c * 64 + 4 * tx);
#pragma unroll
            for (int r = 0; r < 4; r++) {
                float a = sV[(4 * ty + r) * 68 + c];
                acc[r][0] += a * w4.x; acc[r][1] += a * w4.y;
                acc[r][2] += a * w4.z; acc[r][3] += a * w4.w;
            }
        }
        __syncthreads();
#pragma unroll
        for (int r = 0; r < 4; r++)
            st4(sV + (4 * ty + r) * 68 + 4 * tx,
                make_float4(fmaxf(acc[r][0], 0.f), fmaxf(acc[r][1], 0.f),
                            fmaxf(acc[r][2], 0.f), fmaxf(acc[r][3], 0.f)));
        __syncthreads();
    }

    // ---- phase C: O = relu(V @ W2 + b2), store, stats ----
    float acc[4][4];
#pragma unroll
    for (int cc = 0; cc < 4; cc++) {
        float b = b2[4 * tx + cc];
        acc[0][cc] = b; acc[1][cc] = b; acc[2][cc] = b; acc[3][cc] = b;
    }
#pragma unroll 4
    for (int c = 0; c < 64; c++) {
        float4 w4 = ld4(W2 + c * 64 + 4 * tx);
#pragma unroll
        for (int r = 0; r < 4; r++) {
            float a = sV[(4 * ty + r) * 68 + c];
            acc[r][0] += a * w4.x; acc[r][1] += a * w4.y;
            acc[r][2] += a * w4.z; acc[r][3] += a * w4.w;
        }
    }
#pragma unroll
    for (int r = 0; r < 4; r++) {
        int node = base + 4 * ty + r;
        if (node < N) {
            float4 st;
            st.x = fmaxf(acc[r][0], 0.f); st.y = fmaxf(acc[r][1], 0.f);
            st.z = fmaxf(acc[r][2], 0.f); st.w = fmaxf(acc[r][3], 0.f);
            acc[r][0] = st.x; acc[r][1] = st.y; acc[r][2] = st.z; acc[r][3] = st.w;
            st4(hout + (size_t)node * 64 + 4 * tx, st);
        } else {
            acc[r][0] = acc[r][1] = acc[r][2] = acc[r][3] = 0.f;
        }
    }
#pragma unroll
    for (int cc = 0; cc < 4; cc++) {
        float s = 0.f, q = 0.f;
#pragma unroll
        for (int r = 0; r < 4; r++) { s += acc[r][cc]; q += acc[r][cc] * acc[r][cc]; }
        atomicAdd(&sStat[4 * tx + cc], s);
        atomicAdd(&sStat[64 + 4 * tx + cc], q);
    }
    __syncthreads();
    if (tid < 128) atomicAdd(&statsOut[tid], sStat[tid]);
}

// pooled[g] = scale*sum_{n in g} h[n] + cnt*shift; z=relu(p@fc1+b1); z@fc2+b2; log_softmax
__global__ __launch_bounds__(256) void pool_head_kernel(
    const float* __restrict__ h, const int* __restrict__ batch,
    const float* __restrict__ stats, const float* __restrict__ gamma, const float* __restrict__ beta,
    const float* __restrict__ fc1w, const float* __restrict__ fc1b,
    const float* __restrict__ fc2w, const float* __restrict__ fc2b,
    float* __restrict__ out)
{
    __shared__ float sacc[4][64];
    __shared__ float sp[64];
    __shared__ float sz[64];
    __shared__ float so[10];

    int g = blockIdx.x;
    int lane = threadIdx.x & 63, wv = threadIdx.x >> 6;

    int start, end;
    {
        int lo = 0, hi = N;
        while (lo < hi) { int mid = (lo + hi) >> 1; if (batch[mid] < g) lo = mid + 1; else hi = mid; }
        start = lo;
        lo = start; hi = N;
        while (lo < hi) { int mid = (lo + hi) >> 1; if (batch[mid] < g + 1) lo = mid + 1; else hi = mid; }
        end = lo;
    }

    float acc = 0.f;
    for (int node = start + wv; node < end; node += 4)
        acc += h[(size_t)node * 64 + lane];
    sacc[wv][lane] = acc;
    __syncthreads();

    if (wv == 0) {
        float mean = stats[lane] * (1.f / N);
        float var  = stats[64 + lane] * (1.f / N) - mean * mean;
        float sc = gamma[lane] * rsqrtf(var + BN_EPS);
        float sh = beta[lane] - mean * sc;
        float t = sacc[0][lane] + sacc[1][lane] + sacc[2][lane] + sacc[3][lane];
        sp[lane] = sc * t + (float)(end - start) * sh;
    }
    __syncthreads();
    if (wv == 0) {
        float a = fc1b[lane];
#pragma unroll
        for (int c = 0; c < 64; c++) a += sp[c] * fc1w[c * 64 + lane];
        sz[lane] = fmaxf(a, 0.f);
    }
    __syncthreads();
    if (wv == 0 && lane < 10) {
        float z = fc2b[lane];
#pragma unroll
        for (int j = 0; j < 64; j++) z += sz[j] * fc2w[j * 10 + lane];
        so[lane] = z;
    }
    __syncthreads();
    if (wv == 0 && lane < 10) {
        float m = -1e30f;
#pragma unroll
        for (int c = 0; c < 10; c++) m = fmaxf(m, so[c]);
        float s = 0.f;
#pragma unroll
        for (int c = 0; c < 10; c++) s += expf(so[c] - m);
        out[g * 10 + lane] = so[lane] - m - logf(s);
    }
}

extern "C" void kernel_launch(void* const* d_in, const int* in_sizes, int n_in,
                              void* d_out, int out_size, void* d_ws, size_t ws_size,
                              hipStream_t stream)
{
    const float* x    = (const float*)d_in[0];
    const int*   ei   = (const int*)  d_in[1];
    const int*   batch= (const int*)  d_in[2];
    const float* W1a  = (const float*)d_in[3];
    const float* b1a  = (const float*)d_in[4];
    const float* W1b  = (const float*)d_in[5];
    const float* b1b  = (const float*)d_in[6];
    const float* Wa   = (const float*)d_in[7];
    const float* ba   = (const float*)d_in[8];
    const float* Wb   = (const float*)d_in[9];
    const float* bb   = (const float*)d_in[10];
    const float* gammas = (const float*)d_in[11];
    const float* betas  = (const float*)d_in[12];
    const float* fc1w = (const float*)d_in[13];
    const float* fc1b = (const float*)d_in[14];
    const float* fc2w = (const float*)d_in[15];
    const float* fc2b = (const float*)d_in[16];
    float* out = (float*)d_out;

    // workspace carve
    char* w = (char*)d_ws;
    int*   deg   = (int*)w;                          // N ints        @ 0        (zeroed)
    float* stats = (float*)(w + 200000);             // 5*128 floats  @ 200000   (zeroed)
    int*   ell   = (int*)(w + 202752);               // N*64 ints
    float* bufA  = (float*)(w + 13002752);           // (N+1)*64 floats
    float* bufB  = (float*)(w + 25803008);           // (N+1)*64 floats

    hipMemsetAsync(d_ws, 0, 202560, stream);
    hipMemsetAsync(bufA + (size_t)N * 64, 0, 256, stream);   // zero row N
    hipMemsetAsync(bufB + (size_t)N * 64, 0, 256, stream);

    count_fill_kernel<<<(E + 255) / 256, 256, 0, stream>>>(ei, deg, ell);
    pad_kernel<<<(N + 255) / 256, 256, 0, stream>>>(deg, ell);
    xw_kernel<<<(N + 63) / 64, 256, 0, stream>>>(x, W1a, bufA);

    int nb = (N + 63) / 64;

    layer_kernel<true><<<nb, 256, 0, stream>>>(
        bufA, ell, deg, nullptr, nullptr, nullptr, b1a,
        nullptr, nullptr, W1b, b1b, bufB, stats);

    layer_kernel<false><<<nb, 256, 0, stream>>>(
        bufB, ell, deg, stats, gammas, betas, nullptr,
        Wa, ba, Wb, bb, bufA, stats + 128);

    layer_kernel<false><<<nb, 256, 0, stream>>>(
        bufA, ell, deg, stats + 128, gammas + 64, betas + 64, nullptr,
        Wa + 4096, ba + 64, Wb + 4096, bb + 64, bufB, stats + 256);

    layer_kernel<false><<<nb, 256, 0, stream>>>(
        bufB, ell, deg, stats + 256, gammas + 128, betas + 128, nullptr,
        Wa + 8192, ba + 128, Wb + 8192, bb + 128, bufA, stats + 384);

    layer_kernel<false><<<nb, 256, 0, stream>>>(
        bufA, ell, deg, stats + 384, gammas + 192, betas + 192, nullptr,
        Wa + 12288, ba + 192, Wb + 12288, bb + 192, bufB, stats + 512);

    pool_head_kernel<<<G, 256, 0, stream>>>(
        bufB, batch, stats + 512, gammas + 256, betas + 256,
        fc1w, fc1b, fc2w, fc2b, out);
}

// Round 3
// 463.192 us; speedup vs baseline: 1.4204x; 1.1838x over previous
//
#include <hip/hip_runtime.h>
#include <hip/hip_fp16.h>

// GIN (5 layers) + BN + pool + MLP head, fused pipeline for MI355X. Round 5.
// R2 (fp32, 4-chunk): 70us/layer. R3 (more waves): 92us. R4 (16-deep ILP):
// 77us. None of TLP/ILP/VALU/HBM-BW is the limiter -> the invariant is the
// random-gather line stream: 800K rows x 2 cache lines = 1.6M line requests
// per layer at ~2.7 TB/s effective. R5 halves it: node features stored fp16
// (math fp32). Row = 64 halves = exactly ONE 128B line. Gather remapped to
// 8 nodes x 8 feature-octs per wave (16B/lane). Working set 6.4MB ~ L2.

constexpr int N = 50000;
constexpr int E = 800000;
constexpr int G = 128;
constexpr int MAXDEG = 64;
constexpr float BN_EPS = 1e-5f;

__device__ inline float4 ld4(const float* p) { return *(const float4*)p; }
__device__ inline void st4(float* p, float4 v) { *(float4*)p = v; }

// accumulate 8 halves (raw float4 bits) into float a[8]
__device__ inline void acc8(float* a, float4 raw) {
    const __half2* h2 = (const __half2*)&raw;
#pragma unroll
    for (int i = 0; i < 4; i++) {
        float2 f2 = __half22float2(h2[i]);
        a[2 * i] += f2.x; a[2 * i + 1] += f2.y;
    }
}

union HF2 { __half2 h2[2]; float2 f2; };

__global__ __launch_bounds__(256) void count_fill_kernel(
    const int* __restrict__ ei, int* __restrict__ deg, int* __restrict__ ell)
{
    int e = blockIdx.x * 256 + threadIdx.x;
    if (e < E) {
        int s = ei[e];
        int d = ei[E + e];
        int slot = atomicAdd(&deg[d], 1);
        if (slot < MAXDEG) ell[d * MAXDEG + slot] = s;
    }
}

// pad each ELL row to a multiple of 4 slots with the zero-row index N
__global__ __launch_bounds__(256) void pad_kernel(
    const int* __restrict__ deg, int* __restrict__ ell)
{
    int n = blockIdx.x * 256 + threadIdx.x;
    if (n < N) {
        int dgc = min(deg[n], MAXDEG);
        int p = (dgc + 3) & ~3;
        for (int s = dgc; s < p; s++) ell[n * MAXDEG + s] = N;
    }
}

// out[n][64] = x[n][128] @ W[128][64], stored fp16; 64 rows per block
__global__ __launch_bounds__(256) void xw_kernel(
    const float* __restrict__ x, const float* __restrict__ W, __half* __restrict__ out)
{
    int tid = threadIdx.x;
    int ty = tid >> 4, tx = tid & 15;
    int base = blockIdx.x * 64;

    float acc[4][4];
#pragma unroll
    for (int r = 0; r < 4; r++)
#pragma unroll
        for (int cc = 0; cc < 4; cc++) acc[r][cc] = 0.f;

    int rr[4];
#pragma unroll
    for (int r = 0; r < 4; r++) rr[r] = min(base + 4 * ty + r, N - 1);

#pragma unroll 4
    for (int c = 0; c < 128; c++) {
        float4 w4 = ld4(W + c * 64 + 4 * tx);
#pragma unroll
        for (int r = 0; r < 4; r++) {
            float a = x[(size_t)rr[r] * 128 + c];
            acc[r][0] += a * w4.x; acc[r][1] += a * w4.y;
            acc[r][2] += a * w4.z; acc[r][3] += a * w4.w;
        }
    }
#pragma unroll
    for (int r = 0; r < 4; r++) {
        int node = base + 4 * ty + r;
        if (node < N) {
            HF2 u;
            u.h2[0] = __floats2half2_rn(acc[r][0], acc[r][1]);
            u.h2[1] = __floats2half2_rn(acc[r][2], acc[r][3]);
            *(float2*)(out + (size_t)node * 64 + 4 * tx) = u.f2;
        }
    }
}

// Fused GIN layer. hin fp16, N+1 rows (row N = zeros). 64 nodes per block.
// FIRST:  v = relu(own + sum_src + b1a)           then GEMM2(W2,b2)+relu
// !FIRST: v = scale*(own+sum) + (1+deg)*shift, GEMM1(W1,b1)+relu (in-place), GEMM2+relu
// Writes hout fp16 (pre-BN, post-relu) and accumulates channel sum/sumsq into statsOut.
template <bool FIRST>
__global__ __launch_bounds__(256) void layer_kernel(
    const __half* __restrict__ hin, const int* __restrict__ ell, const int* __restrict__ deg,
    const float* __restrict__ statsPrev, const float* __restrict__ gamma, const float* __restrict__ beta,
    const float* __restrict__ bias0,
    const float* __restrict__ W1, const float* __restrict__ b1,
    const float* __restrict__ W2, const float* __restrict__ b2,
    __half* __restrict__ hout, float* __restrict__ statsOut)
{
    __shared__ float sV[64 * 68];   // stride 68
    __shared__ float sStat[128];

    int tid = threadIdx.x, lane = tid & 63, wv = tid >> 6;
    if (tid < 128) sStat[tid] = 0.f;

    int base = blockIdx.x * 64;
    int n8 = lane >> 3, f = lane & 7;   // node-sub (8), feature-oct (8)

    // per-lane channel oct f*8..f*8+7 epilogue params
    float sc[8], sh[8], b0[8];
    if constexpr (FIRST) {
#pragma unroll
        for (int q = 0; q < 2; q++) {
            float4 b4 = ld4(bias0 + 8 * f + 4 * q);
            b0[4 * q + 0] = b4.x; b0[4 * q + 1] = b4.y;
            b0[4 * q + 2] = b4.z; b0[4 * q + 3] = b4.w;
        }
    } else {
#pragma unroll
        for (int q = 0; q < 2; q++) {
            float4 s1 = ld4(statsPrev + 8 * f + 4 * q);
            float4 s2 = ld4(statsPrev + 64 + 8 * f + 4 * q);
            float4 g4 = ld4(gamma + 8 * f + 4 * q);
            float4 be4 = ld4(beta + 8 * f + 4 * q);
            float m[4] = { s1.x / N, s1.y / N, s1.z / N, s1.w / N };
            float v2[4] = { s2.x / N, s2.y / N, s2.z / N, s2.w / N };
            float gg[4] = { g4.x, g4.y, g4.z, g4.w };
            float bb4[4] = { be4.x, be4.y, be4.z, be4.w };
#pragma unroll
            for (int i = 0; i < 4; i++) {
                float s = gg[i] * rsqrtf(v2[i] - m[i] * m[i] + BN_EPS);
                sc[4 * q + i] = s;
                sh[4 * q + i] = bb4[i] - m[i] * s;
            }
        }
    }

    // ---- phase A: gather; wave handles 8 nodes at a time, 2 rounds ----
#pragma unroll
    for (int kk = 0; kk < 2; kk++) {
        int node = base + wv * 16 + kk * 8 + n8;
        int nd = (node < N) ? node : N;
        int dg = (node < N) ? deg[node] : 0;
        int dgc = min(dg, MAXDEG);
        int p = (dgc + 3) & ~3;
        const int* row = ell + (size_t)nd * MAXDEG;

        float a0[8], a1[8], a2[8], a3[8];
#pragma unroll
        for (int i = 0; i < 8; i++) { a0[i] = 0.f; a1[i] = 0.f; a2[i] = 0.f; a3[i] = 0.f; }

        float4 rown = ld4((const float*)(hin + (size_t)nd * 64 + 8 * f));
        for (int j = 0; j < p; j += 4) {
            int4 iv = *(const int4*)(row + j);
            float4 r0 = ld4((const float*)(hin + (size_t)iv.x * 64 + 8 * f));
            float4 r1 = ld4((const float*)(hin + (size_t)iv.y * 64 + 8 * f));
            float4 r2 = ld4((const float*)(hin + (size_t)iv.z * 64 + 8 * f));
            float4 r3 = ld4((const float*)(hin + (size_t)iv.w * 64 + 8 * f));
            acc8(a0, r0); acc8(a1, r1); acc8(a2, r2); acc8(a3, r3);
        }
        acc8(a0, rown);

        float v[8];
#pragma unroll
        for (int i = 0; i < 8; i++) {
            float s = (a0[i] + a1[i]) + (a2[i] + a3[i]);
            if constexpr (FIRST) {
                v[i] = fmaxf(s + b0[i], 0.f);
            } else {
                v[i] = sc[i] * s + (float)(1 + dg) * sh[i];
            }
        }
        int ridx = wv * 16 + kk * 8 + n8;
        st4(sV + ridx * 68 + 8 * f,     make_float4(v[0], v[1], v[2], v[3]));
        st4(sV + ridx * 68 + 8 * f + 4, make_float4(v[4], v[5], v[6], v[7]));
    }
    __syncthreads();

    int ty = tid >> 4, tx = tid & 15;

    if constexpr (!FIRST) {
        // ---- phase B: H = relu(V @ W1 + b1), in-place into sV ----
        float acc[4][4];
#pragma unroll
        for (int cc = 0; cc < 4; cc++) {
            float b = b1[4 * tx + cc];
            acc[0][cc] = b; acc[1][cc] = b; acc[2][cc] = b; acc[3][cc] = b;
        }
#pragma unroll 4
        for (int c = 0; c < 64; c++) {
            float4 w4 = ld4(W1 + c * 64 + 4 * tx);
#pragma unroll
            for (int r = 0; r < 4; r++) {
                float a = sV[(4 * ty + r) * 68 + c];
                acc[r][0] += a * w4.x; acc[r][1] += a * w4.y;
                acc[r][2] += a * w4.z; acc[r][3] += a * w4.w;
            }
        }
        __syncthreads();
#pragma unroll
        for (int r = 0; r < 4; r++)
            st4(sV + (4 * ty + r) * 68 + 4 * tx,
                make_float4(fmaxf(acc[r][0], 0.f), fmaxf(acc[r][1], 0.f),
                            fmaxf(acc[r][2], 0.f), fmaxf(acc[r][3], 0.f)));
        __syncthreads();
    }

    // ---- phase C: O = relu(V @ W2 + b2), store fp16, stats fp32 ----
    float acc[4][4];
#pragma unroll
    for (int cc = 0; cc < 4; cc++) {
        float b = b2[4 * tx + cc];
        acc[0][cc] = b; acc[1][cc] = b; acc[2][cc] = b; acc[3][cc] = b;
    }
#pragma unroll 4
    for (int c = 0; c < 64; c++) {
        float4 w4 = ld4(W2 + c * 64 + 4 * tx);
#pragma unroll
        for (int r = 0; r < 4; r++) {
            float a = sV[(4 * ty + r) * 68 + c];
            acc[r][0] += a * w4.x; acc[r][1] += a * w4.y;
            acc[r][2] += a * w4.z; acc[r][3] += a * w4.w;
        }
    }
#pragma unroll
    for (int r = 0; r < 4; r++) {
        int node = base + 4 * ty + r;
        if (node < N) {
            acc[r][0] = fmaxf(acc[r][0], 0.f); acc[r][1] = fmaxf(acc[r][1], 0.f);
            acc[r][2] = fmaxf(acc[r][2], 0.f); acc[r][3] = fmaxf(acc[r][3], 0.f);
            HF2 u;
            u.h2[0] = __floats2half2_rn(acc[r][0], acc[r][1]);
            u.h2[1] = __floats2half2_rn(acc[r][2], acc[r][3]);
            *(float2*)(hout + (size_t)node * 64 + 4 * tx) = u.f2;
        } else {
            acc[r][0] = acc[r][1] = acc[r][2] = acc[r][3] = 0.f;
        }
    }
#pragma unroll
    for (int cc = 0; cc < 4; cc++) {
        float s = 0.f, q = 0.f;
#pragma unroll
        for (int r = 0; r < 4; r++) { s += acc[r][cc]; q += acc[r][cc] * acc[r][cc]; }
        atomicAdd(&sStat[4 * tx + cc], s);
        atomicAdd(&sStat[64 + 4 * tx + cc], q);
    }
    __syncthreads();
    if (tid < 128) atomicAdd(&statsOut[tid], sStat[tid]);
}

// pooled[g] = scale*sum_{n in g} h[n] + cnt*shift; z=relu(p@fc1+b1); z@fc2+b2; log_softmax
__global__ __launch_bounds__(256) void pool_head_kernel(
    const __half* __restrict__ h, const int* __restrict__ batch,
    const float* __restrict__ stats, const float* __restrict__ gamma, const float* __restrict__ beta,
    const float* __restrict__ fc1w, const float* __restrict__ fc1b,
    const float* __restrict__ fc2w, const float* __restrict__ fc2b,
    float* __restrict__ out)
{
    __shared__ float sacc[4][64];
    __shared__ float sp[64];
    __shared__ float sz[64];
    __shared__ float so[10];

    int g = blockIdx.x;
    int lane = threadIdx.x & 63, wv = threadIdx.x >> 6;

    int start, end;
    {
        int lo = 0, hi = N;
        while (lo < hi) { int mid = (lo + hi) >> 1; if (batch[mid] < g) lo = mid + 1; else hi = mid; }
        start = lo;
        lo = start; hi = N;
        while (lo < hi) { int mid = (lo + hi) >> 1; if (batch[mid] < g + 1) lo = mid + 1; else hi = mid; }
        end = lo;
    }

    float acc = 0.f;
    for (int node = start + wv; node < end; node += 4)
        acc += __half2float(h[(size_t)node * 64 + lane]);
    sacc[wv][lane] = acc;
    __syncthreads();

    if (wv == 0) {
        float mean = stats[lane] * (1.f / N);
        float var  = stats[64 + lane] * (1.f / N) - mean * mean;
        float sc = gamma[lane] * rsqrtf(var + BN_EPS);
        float sh = beta[lane] - mean * sc;
        float t = sacc[0][lane] + sacc[1][lane] + sacc[2][lane] + sacc[3][lane];
        sp[lane] = sc * t + (float)(end - start) * sh;
    }
    __syncthreads();
    if (wv == 0) {
        float a = fc1b[lane];
#pragma unroll
        for (int c = 0; c < 64; c++) a += sp[c] * fc1w[c * 64 + lane];
        sz[lane] = fmaxf(a, 0.f);
    }
    __syncthreads();
    if (wv == 0 && lane < 10) {
        float z = fc2b[lane];
#pragma unroll
        for (int j = 0; j < 64; j++) z += sz[j] * fc2w[j * 10 + lane];
        so[lane] = z;
    }
    __syncthreads();
    if (wv == 0 && lane < 10) {
        float m = -1e30f;
#pragma unroll
        for (int c = 0; c < 10; c++) m = fmaxf(m, so[c]);
        float s = 0.f;
#pragma unroll
        for (int c = 0; c < 10; c++) s += expf(so[c] - m);
        out[g * 10 + lane] = so[lane] - m - logf(s);
    }
}

extern "C" void kernel_launch(void* const* d_in, const int* in_sizes, int n_in,
                              void* d_out, int out_size, void* d_ws, size_t ws_size,
                              hipStream_t stream)
{
    const float* x    = (const float*)d_in[0];
    const int*   ei   = (const int*)  d_in[1];
    const int*   batch= (const int*)  d_in[2];
    const float* W1a  = (const float*)d_in[3];
    const float* b1a  = (const float*)d_in[4];
    const float* W1b  = (const float*)d_in[5];
    const float* b1b  = (const float*)d_in[6];
    const float* Wa   = (const float*)d_in[7];
    const float* ba   = (const float*)d_in[8];
    const float* Wb   = (const float*)d_in[9];
    const float* bb   = (const float*)d_in[10];
    const float* gammas = (const float*)d_in[11];
    const float* betas  = (const float*)d_in[12];
    const float* fc1w = (const float*)d_in[13];
    const float* fc1b = (const float*)d_in[14];
    const float* fc2w = (const float*)d_in[15];
    const float* fc2b = (const float*)d_in[16];
    float* out = (float*)d_out;

    // workspace carve
    char* w = (char*)d_ws;
    int*    deg   = (int*)w;                         // N ints        @ 0        (zeroed)
    float*  stats = (float*)(w + 200000);            // 5*128 floats  @ 200000   (zeroed)
    int*    ell   = (int*)(w + 202752);              // N*64 ints     -> ends 13,002,752
    __half* bufA  = (__half*)(w + 13002752);         // (N+1)*64 halves = 6,400,128 B
    __half* bufB  = (__half*)(w + 19403008);         // (N+1)*64 halves

    hipMemsetAsync(d_ws, 0, 202560, stream);
    hipMemsetAsync(bufA + (size_t)N * 64, 0, 128, stream);   // zero row N
    hipMemsetAsync(bufB + (size_t)N * 64, 0, 128, stream);

    count_fill_kernel<<<(E + 255) / 256, 256, 0, stream>>>(ei, deg, ell);
    pad_kernel<<<(N + 255) / 256, 256, 0, stream>>>(deg, ell);
    xw_kernel<<<(N + 63) / 64, 256, 0, stream>>>(x, W1a, bufA);

    int nb = (N + 63) / 64;

    layer_kernel<true><<<nb, 256, 0, stream>>>(
        bufA, ell, deg, nullptr, nullptr, nullptr, b1a,
        nullptr, nullptr, W1b, b1b, bufB, stats);

    layer_kernel<false><<<nb, 256, 0, stream>>>(
        bufB, ell, deg, stats, gammas, betas, nullptr,
        Wa, ba, Wb, bb, bufA, stats + 128);

    layer_kernel<false><<<nb, 256, 0, stream>>>(
        bufA, ell, deg, stats + 128, gammas + 64, betas + 64, nullptr,
        Wa + 4096, ba + 64, Wb + 4096, bb + 64, bufB, stats + 256);

    layer_kernel<false><<<nb, 256, 0, stream>>>(
        bufB, ell, deg, stats + 256, gammas + 128, betas + 128, nullptr,
        Wa + 8192, ba + 128, Wb + 8192, bb + 128, bufA, stats + 384);

    layer_kernel<false><<<nb, 256, 0, stream>>>(
        bufA, ell, deg, stats + 384, gammas + 192, betas + 192, nullptr,
        Wa + 12288, ba + 192, Wb + 12288, bb + 192, bufB, stats + 512);

    pool_head_kernel<<<G, 256, 0, stream>>>(
        bufB, batch, stats + 512, gammas + 256, betas + 256,
        fc1w, fc1b, fc2w, fc2b, out);
}

// Round 4
// 450.177 us; speedup vs baseline: 1.4615x; 1.0289x over previous
//
#include <hip/hip_runtime.h>
#include <hip/hip_fp16.h>

// GIN (5 layers) + BN + pool + MLP head, fused pipeline for MI355X. Round 6.
// R5 (fp16 rows): 58us/layer, FETCH halved but time -17% only. GEMMs proven
// free (1-GEMM FIRST layer == 2-GEMM layers). Invariant across R2-R5: every
// block fires 128 global atomicAdds into the SAME 512B (stats) -> 100K
// lane-atomics/layer onto 4 cache lines ~ 42us of serialized RMW at the
// owning L2. R6: atomic-free stats. Blocks write coalesced per-block
// partials (512B each); reduce_stats_kernel<<<128,64>>> folds 782x128 ->
// 128 between layers (~2us). Gather/GEMM untouched to isolate the effect.

constexpr int N = 50000;
constexpr int E = 800000;
constexpr int G = 128;
constexpr int MAXDEG = 64;
constexpr float BN_EPS = 1e-5f;

__device__ inline float4 ld4(const float* p) { return *(const float4*)p; }
__device__ inline void st4(float* p, float4 v) { *(float4*)p = v; }

// accumulate 8 halves (raw float4 bits) into float a[8]
__device__ inline void acc8(float* a, float4 raw) {
    const __half2* h2 = (const __half2*)&raw;
#pragma unroll
    for (int i = 0; i < 4; i++) {
        float2 f2 = __half22float2(h2[i]);
        a[2 * i] += f2.x; a[2 * i + 1] += f2.y;
    }
}

union HF2 { __half2 h2[2]; float2 f2; };

__global__ __launch_bounds__(256) void count_fill_kernel(
    const int* __restrict__ ei, int* __restrict__ deg, int* __restrict__ ell)
{
    int e = blockIdx.x * 256 + threadIdx.x;
    if (e < E) {
        int s = ei[e];
        int d = ei[E + e];
        int slot = atomicAdd(&deg[d], 1);
        if (slot < MAXDEG) ell[d * MAXDEG + slot] = s;
    }
}

// pad each ELL row to a multiple of 4 slots with the zero-row index N
__global__ __launch_bounds__(256) void pad_kernel(
    const int* __restrict__ deg, int* __restrict__ ell)
{
    int n = blockIdx.x * 256 + threadIdx.x;
    if (n < N) {
        int dgc = min(deg[n], MAXDEG);
        int p = (dgc + 3) & ~3;
        for (int s = dgc; s < p; s++) ell[n * MAXDEG + s] = N;
    }
}

// out[n][64] = x[n][128] @ W[128][64], stored fp16; 64 rows per block
__global__ __launch_bounds__(256) void xw_kernel(
    const float* __restrict__ x, const float* __restrict__ W, __half* __restrict__ out)
{
    int tid = threadIdx.x;
    int ty = tid >> 4, tx = tid & 15;
    int base = blockIdx.x * 64;

    float acc[4][4];
#pragma unroll
    for (int r = 0; r < 4; r++)
#pragma unroll
        for (int cc = 0; cc < 4; cc++) acc[r][cc] = 0.f;

    int rr[4];
#pragma unroll
    for (int r = 0; r < 4; r++) rr[r] = min(base + 4 * ty + r, N - 1);

#pragma unroll 4
    for (int c = 0; c < 128; c++) {
        float4 w4 = ld4(W + c * 64 + 4 * tx);
#pragma unroll
        for (int r = 0; r < 4; r++) {
            float a = x[(size_t)rr[r] * 128 + c];
            acc[r][0] += a * w4.x; acc[r][1] += a * w4.y;
            acc[r][2] += a * w4.z; acc[r][3] += a * w4.w;
        }
    }
#pragma unroll
    for (int r = 0; r < 4; r++) {
        int node = base + 4 * ty + r;
        if (node < N) {
            HF2 u;
            u.h2[0] = __floats2half2_rn(acc[r][0], acc[r][1]);
            u.h2[1] = __floats2half2_rn(acc[r][2], acc[r][3]);
            *(float2*)(out + (size_t)node * 64 + 4 * tx) = u.f2;
        }
    }
}

// sum 782 per-block partials (each 128 floats) into stats[128].
// block c owns channel c; 64 lanes stride the blocks; shuffle-reduce.
__global__ __launch_bounds__(64) void reduce_stats_kernel(
    const float* __restrict__ partials, float* __restrict__ stats, int nb)
{
    int c = blockIdx.x;
    int lane = threadIdx.x;
    float s = 0.f;
    for (int i = lane; i < nb; i += 64)
        s += partials[(size_t)i * 128 + c];
#pragma unroll
    for (int off = 32; off > 0; off >>= 1)
        s += __shfl_down(s, off, 64);
    if (lane == 0) stats[c] = s;
}

// Fused GIN layer. hin fp16, N+1 rows (row N = zeros). 64 nodes per block.
// FIRST:  v = relu(own + sum_src + b1a)           then GEMM2(W2,b2)+relu
// !FIRST: v = scale*(own+sum) + (1+deg)*shift, GEMM1(W1,b1)+relu (in-place), GEMM2+relu
// Writes hout fp16 (pre-BN, post-relu); writes per-block channel sum/sumsq
// partials to statsPart[blockIdx*128 + 0..127] (NO global atomics).
template <bool FIRST>
__global__ __launch_bounds__(256) void layer_kernel(
    const __half* __restrict__ hin, const int* __restrict__ ell, const int* __restrict__ deg,
    const float* __restrict__ statsPrev, const float* __restrict__ gamma, const float* __restrict__ beta,
    const float* __restrict__ bias0,
    const float* __restrict__ W1, const float* __restrict__ b1,
    const float* __restrict__ W2, const float* __restrict__ b2,
    __half* __restrict__ hout, float* __restrict__ statsPart)
{
    __shared__ float sV[64 * 68];   // stride 68
    __shared__ float sStat[128];

    int tid = threadIdx.x, lane = tid & 63, wv = tid >> 6;
    if (tid < 128) sStat[tid] = 0.f;

    int base = blockIdx.x * 64;
    int n8 = lane >> 3, f = lane & 7;   // node-sub (8), feature-oct (8)

    // per-lane channel oct f*8..f*8+7 epilogue params
    float sc[8], sh[8], b0[8];
    if constexpr (FIRST) {
#pragma unroll
        for (int q = 0; q < 2; q++) {
            float4 b4 = ld4(bias0 + 8 * f + 4 * q);
            b0[4 * q + 0] = b4.x; b0[4 * q + 1] = b4.y;
            b0[4 * q + 2] = b4.z; b0[4 * q + 3] = b4.w;
        }
    } else {
#pragma unroll
        for (int q = 0; q < 2; q++) {
            float4 s1 = ld4(statsPrev + 8 * f + 4 * q);
            float4 s2 = ld4(statsPrev + 64 + 8 * f + 4 * q);
            float4 g4 = ld4(gamma + 8 * f + 4 * q);
            float4 be4 = ld4(beta + 8 * f + 4 * q);
            float m[4] = { s1.x / N, s1.y / N, s1.z / N, s1.w / N };
            float v2[4] = { s2.x / N, s2.y / N, s2.z / N, s2.w / N };
            float gg[4] = { g4.x, g4.y, g4.z, g4.w };
            float bb4[4] = { be4.x, be4.y, be4.z, be4.w };
#pragma unroll
            for (int i = 0; i < 4; i++) {
                float s = gg[i] * rsqrtf(v2[i] - m[i] * m[i] + BN_EPS);
                sc[4 * q + i] = s;
                sh[4 * q + i] = bb4[i] - m[i] * s;
            }
        }
    }

    // ---- phase A: gather; wave handles 8 nodes at a time, 2 rounds ----
#pragma unroll
    for (int kk = 0; kk < 2; kk++) {
        int node = base + wv * 16 + kk * 8 + n8;
        int nd = (node < N) ? node : N;
        int dg = (node < N) ? deg[node] : 0;
        int dgc = min(dg, MAXDEG);
        int p = (dgc + 3) & ~3;
        const int* row = ell + (size_t)nd * MAXDEG;

        float a0[8], a1[8], a2[8], a3[8];
#pragma unroll
        for (int i = 0; i < 8; i++) { a0[i] = 0.f; a1[i] = 0.f; a2[i] = 0.f; a3[i] = 0.f; }

        float4 rown = ld4((const float*)(hin + (size_t)nd * 64 + 8 * f));
        for (int j = 0; j < p; j += 4) {
            int4 iv = *(const int4*)(row + j);
            float4 r0 = ld4((const float*)(hin + (size_t)iv.x * 64 + 8 * f));
            float4 r1 = ld4((const float*)(hin + (size_t)iv.y * 64 + 8 * f));
            float4 r2 = ld4((const float*)(hin + (size_t)iv.z * 64 + 8 * f));
            float4 r3 = ld4((const float*)(hin + (size_t)iv.w * 64 + 8 * f));
            acc8(a0, r0); acc8(a1, r1); acc8(a2, r2); acc8(a3, r3);
        }
        acc8(a0, rown);

        float v[8];
#pragma unroll
        for (int i = 0; i < 8; i++) {
            float s = (a0[i] + a1[i]) + (a2[i] + a3[i]);
            if constexpr (FIRST) {
                v[i] = fmaxf(s + b0[i], 0.f);
            } else {
                v[i] = sc[i] * s + (float)(1 + dg) * sh[i];
            }
        }
        int ridx = wv * 16 + kk * 8 + n8;
        st4(sV + ridx * 68 + 8 * f,     make_float4(v[0], v[1], v[2], v[3]));
        st4(sV + ridx * 68 + 8 * f + 4, make_float4(v[4], v[5], v[6], v[7]));
    }
    __syncthreads();

    int ty = tid >> 4, tx = tid & 15;

    if constexpr (!FIRST) {
        // ---- phase B: H = relu(V @ W1 + b1), in-place into sV ----
        float acc[4][4];
#pragma unroll
        for (int cc = 0; cc < 4; cc++) {
            float b = b1[4 * tx + cc];
            acc[0][cc] = b; acc[1][cc] = b; acc[2][cc] = b; acc[3][cc] = b;
        }
#pragma unroll 4
        for (int c = 0; c < 64; c++) {
            float4 w4 = ld4(W1 + c * 64 + 4 * tx);
#pragma unroll
            for (int r = 0; r < 4; r++) {
                float a = sV[(4 * ty + r) * 68 + c];
                acc[r][0] += a * w4.x; acc[r][1] += a * w4.y;
                acc[r][2] += a * w4.z; acc[r][3] += a * w4.w;
            }
        }
        __syncthreads();
#pragma unroll
        for (int r = 0; r < 4; r++)
            st4(sV + (4 * ty + r) * 68 + 4 * tx,
                make_float4(fmaxf(acc[r][0], 0.f), fmaxf(acc[r][1], 0.f),
                            fmaxf(acc[r][2], 0.f), fmaxf(acc[r][3], 0.f)));
        __syncthreads();
    }

    // ---- phase C: O = relu(V @ W2 + b2), store fp16, stats fp32 ----
    float acc[4][4];
#pragma unroll
    for (int cc = 0; cc < 4; cc++) {
        float b = b2[4 * tx + cc];
        acc[0][cc] = b; acc[1][cc] = b; acc[2][cc] = b; acc[3][cc] = b;
    }
#pragma unroll 4
    for (int c = 0; c < 64; c++) {
        float4 w4 = ld4(W2 + c * 64 + 4 * tx);
#pragma unroll
        for (int r = 0; r < 4; r++) {
            float a = sV[(4 * ty + r) * 68 + c];
            acc[r][0] += a * w4.x; acc[r][1] += a * w4.y;
            acc[r][2] += a * w4.z; acc[r][3] += a * w4.w;
        }
    }
#pragma unroll
    for (int r = 0; r < 4; r++) {
        int node = base + 4 * ty + r;
        if (node < N) {
            acc[r][0] = fmaxf(acc[r][0], 0.f); acc[r][1] = fmaxf(acc[r][1], 0.f);
            acc[r][2] = fmaxf(acc[r][2], 0.f); acc[r][3] = fmaxf(acc[r][3], 0.f);
            HF2 u;
            u.h2[0] = __floats2half2_rn(acc[r][0], acc[r][1]);
            u.h2[1] = __floats2half2_rn(acc[r][2], acc[r][3]);
            *(float2*)(hout + (size_t)node * 64 + 4 * tx) = u.f2;
        } else {
            acc[r][0] = acc[r][1] = acc[r][2] = acc[r][3] = 0.f;
        }
    }
#pragma unroll
    for (int cc = 0; cc < 4; cc++) {
        float s = 0.f, q = 0.f;
#pragma unroll
        for (int r = 0; r < 4; r++) { s += acc[r][cc]; q += acc[r][cc] * acc[r][cc]; }
        atomicAdd(&sStat[4 * tx + cc], s);
        atomicAdd(&sStat[64 + 4 * tx + cc], q);
    }
    __syncthreads();
    if (tid < 128) statsPart[(size_t)blockIdx.x * 128 + tid] = sStat[tid];
}

// pooled[g] = scale*sum_{n in g} h[n] + cnt*shift; z=relu(p@fc1+b1); z@fc2+b2; log_softmax
__global__ __launch_bounds__(256) void pool_head_kernel(
    const __half* __restrict__ h, const int* __restrict__ batch,
    const float* __restrict__ stats, const float* __restrict__ gamma, const float* __restrict__ beta,
    const float* __restrict__ fc1w, const float* __restrict__ fc1b,
    const float* __restrict__ fc2w, const float* __restrict__ fc2b,
    float* __restrict__ out)
{
    __shared__ float sacc[4][64];
    __shared__ float sp[64];
    __shared__ float sz[64];
    __shared__ float so[10];

    int g = blockIdx.x;
    int lane = threadIdx.x & 63, wv = threadIdx.x >> 6;

    int start, end;
    {
        int lo = 0, hi = N;
        while (lo < hi) { int mid = (lo + hi) >> 1; if (batch[mid] < g) lo = mid + 1; else hi = mid; }
        start = lo;
        lo = start; hi = N;
        while (lo < hi) { int mid = (lo + hi) >> 1; if (batch[mid] < g + 1) lo = mid + 1; else hi = mid; }
        end = lo;
    }

    float acc = 0.f;
    for (int node = start + wv; node < end; node += 4)
        acc += __half2float(h[(size_t)node * 64 + lane]);
    sacc[wv][lane] = acc;
    __syncthreads();

    if (wv == 0) {
        float mean = stats[lane] * (1.f / N);
        float var  = stats[64 + lane] * (1.f / N) - mean * mean;
        float sc = gamma[lane] * rsqrtf(var + BN_EPS);
        float sh = beta[lane] - mean * sc;
        float t = sacc[0][lane] + sacc[1][lane] + sacc[2][lane] + sacc[3][lane];
        sp[lane] = sc * t + (float)(end - start) * sh;
    }
    __syncthreads();
    if (wv == 0) {
        float a = fc1b[lane];
#pragma unroll
        for (int c = 0; c < 64; c++) a += sp[c] * fc1w[c * 64 + lane];
        sz[lane] = fmaxf(a, 0.f);
    }
    __syncthreads();
    if (wv == 0 && lane < 10) {
        float z = fc2b[lane];
#pragma unroll
        for (int j = 0; j < 64; j++) z += sz[j] * fc2w[j * 10 + lane];
        so[lane] = z;
    }
    __syncthreads();
    if (wv == 0 && lane < 10) {
        float m = -1e30f;
#pragma unroll
        for (int c = 0; c < 10; c++) m = fmaxf(m, so[c]);
        float s = 0.f;
#pragma unroll
        for (int c = 0; c < 10; c++) s += expf(so[c] - m);
        out[g * 10 + lane] = so[lane] - m - logf(s);
    }
}

extern "C" void kernel_launch(void* const* d_in, const int* in_sizes, int n_in,
                              void* d_out, int out_size, void* d_ws, size_t ws_size,
                              hipStream_t stream)
{
    const float* x    = (const float*)d_in[0];
    const int*   ei   = (const int*)  d_in[1];
    const int*   batch= (const int*)  d_in[2];
    const float* W1a  = (const float*)d_in[3];
    const float* b1a  = (const float*)d_in[4];
    const float* W1b  = (const float*)d_in[5];
    const float* b1b  = (const float*)d_in[6];
    const float* Wa   = (const float*)d_in[7];
    const float* ba   = (const float*)d_in[8];
    const float* Wb   = (const float*)d_in[9];
    const float* bb   = (const float*)d_in[10];
    const float* gammas = (const float*)d_in[11];
    const float* betas  = (const float*)d_in[12];
    const float* fc1w = (const float*)d_in[13];
    const float* fc1b = (const float*)d_in[14];
    const float* fc2w = (const float*)d_in[15];
    const float* fc2b = (const float*)d_in[16];
    float* out = (float*)d_out;

    // workspace carve
    char* w = (char*)d_ws;
    int*    deg     = (int*)w;                       // N ints        @ 0        (zeroed)
    float*  stats   = (float*)(w + 200000);          // 5*128 floats  @ 200000
    int*    ell     = (int*)(w + 202752);            // N*64 ints     -> ends 13,002,752
    __half* bufA    = (__half*)(w + 13002752);       // (N+1)*64 halves = 6,400,128 B
    __half* bufB    = (__half*)(w + 19403008);       // (N+1)*64 halves -> ends 25,803,136
    float*  partials= (float*)(w + 25803136);        // nb*128 floats = 400,384 B

    hipMemsetAsync(d_ws, 0, 200000, stream);                 // deg only
    hipMemsetAsync(bufA + (size_t)N * 64, 0, 128, stream);   // zero row N
    hipMemsetAsync(bufB + (size_t)N * 64, 0, 128, stream);

    count_fill_kernel<<<(E + 255) / 256, 256, 0, stream>>>(ei, deg, ell);
    pad_kernel<<<(N + 255) / 256, 256, 0, stream>>>(deg, ell);
    xw_kernel<<<(N + 63) / 64, 256, 0, stream>>>(x, W1a, bufA);

    int nb = (N + 63) / 64;

    layer_kernel<true><<<nb, 256, 0, stream>>>(
        bufA, ell, deg, nullptr, nullptr, nullptr, b1a,
        nullptr, nullptr, W1b, b1b, bufB, partials);
    reduce_stats_kernel<<<128, 64, 0, stream>>>(partials, stats, nb);

    layer_kernel<false><<<nb, 256, 0, stream>>>(
        bufB, ell, deg, stats, gammas, betas, nullptr,
        Wa, ba, Wb, bb, bufA, partials);
    reduce_stats_kernel<<<128, 64, 0, stream>>>(partials, stats + 128, nb);

    layer_kernel<false><<<nb, 256, 0, stream>>>(
        bufA, ell, deg, stats + 128, gammas + 64, betas + 64, nullptr,
        Wa + 4096, ba + 64, Wb + 4096, bb + 64, bufB, partials);
    reduce_stats_kernel<<<128, 64, 0, stream>>>(partials, stats + 256, nb);

    layer_kernel<false><<<nb, 256, 0, stream>>>(
        bufB, ell, deg, stats + 256, gammas + 128, betas + 128, nullptr,
        Wa + 8192, ba + 128, Wb + 8192, bb + 128, bufA, partials);
    reduce_stats_kernel<<<128, 64, 0, stream>>>(partials, stats + 384, nb);

    layer_kernel<false><<<nb, 256, 0, stream>>>(
        bufA, ell, deg, stats + 384, gammas + 192, betas + 192, nullptr,
        Wa + 12288, ba + 192, Wb + 12288, bb + 192, bufB, partials);
    reduce_stats_kernel<<<128, 64, 0, stream>>>(partials, stats + 512, nb);

    pool_head_kernel<<<G, 256, 0, stream>>>(
        bufB, batch, stats + 512, gammas + 256, betas + 256,
        fc1w, fc1b, fc2w, fc2b, out);
}